// Round 16
// baseline (151.473 us; speedup 1.0000x reference)
//
#include <hip/hip_runtime.h>
#include <stdint.h>
#include <stddef.h>

#define SEQ 2048
#define NH 16
#define HD 64
#define NB 2
#define HID 1024

typedef short bf16x8 __attribute__((ext_vector_type(8)));
typedef unsigned short ushort8 __attribute__((ext_vector_type(8)));
typedef float f32x4 __attribute__((ext_vector_type(4)));
typedef float f32x16 __attribute__((ext_vector_type(16)));
typedef unsigned u32x2 __attribute__((ext_vector_type(2)));

__device__ __forceinline__ unsigned short f2bf(float f) {
  unsigned u = __float_as_uint(f);
  u += 0x7fffu + ((u >> 16) & 1u);
  return (unsigned short)(u >> 16);
}

__device__ __forceinline__ unsigned cvtpk(float lo, float hi) {
  unsigned d;
  asm("v_cvt_pk_bf16_f32 %0, %1, %2" : "=v"(d) : "v"(lo), "v"(hi));
  return d;
}

// bare v_exp_f32 (2^x): exp2f() lowers to the slow precise OCML path (r7 lesson)
__device__ __forceinline__ float fexp2(float x) {
  float d;
  asm("v_exp_f32 %0, %1" : "=v"(d) : "v"(x));
  return d;
}

__device__ __forceinline__ void load_lds16(const void* g, void* l) {
  __builtin_amdgcn_global_load_lds(
      (const __attribute__((address_space(1))) unsigned int*)g,
      (__attribute__((address_space(3))) unsigned int*)l, 16, 0, 0);
}

// ---------------- fused: fp32->bf16 convert (x + 4 weights) & mask map ------
// blocks [0,4096): convert 8 floats/thread (4096*256*8 = 8388608 elements,
// exactly x + 4 weights); blocks [4096,5120): mask -> 64x64 any-zero map.
__global__ __launch_bounds__(256) void convert_and_mask(
    const float* __restrict__ x, const float* __restrict__ wq,
    const float* __restrict__ wk, const float* __restrict__ wv,
    const float* __restrict__ wo, const int* __restrict__ mask,
    unsigned short* __restrict__ dst, int* __restrict__ map) {
  const int bid = blockIdx.x;
  if (bid < 4096) {
    long i = ((long)bid * 256 + threadIdx.x) * 8;
    const float* src; long off;
    if (i < 4194304L)      { src = x;  off = i; }
    else if (i < 5242880L) { src = wq; off = i - 4194304L; }
    else if (i < 6291456L) { src = wk; off = i - 5242880L; }
    else if (i < 7340032L) { src = wv; off = i - 6291456L; }
    else                   { src = wo; off = i - 7340032L; }
    float4 a = *reinterpret_cast<const float4*>(src + off);
    float4 b = *reinterpret_cast<const float4*>(src + off + 4);
    ushort8 o;
    o[0] = f2bf(a.x); o[1] = f2bf(a.y); o[2] = f2bf(a.z); o[3] = f2bf(a.w);
    o[4] = f2bf(b.x); o[5] = f2bf(b.y); o[6] = f2bf(b.z); o[7] = f2bf(b.w);
    *reinterpret_cast<ushort8*>(dst + i) = o;
  } else {
    const int b2 = bid - 4096;
    const int qb = b2 >> 5, kb = b2 & 31;
    int bad = 0;
    for (int i = threadIdx.x; i < 4096; i += 256) {
      int qq = i >> 6, kk = i & 63;
      bad |= (mask[(size_t)(qb * 64 + qq) * SEQ + kb * 64 + kk] == 0);
    }
    __shared__ int red[4];
    unsigned long long any = __ballot(bad);
    if ((threadIdx.x & 63) == 0) red[threadIdx.x >> 6] = (any != 0ULL);
    __syncthreads();
    if (threadIdx.x == 0) map[qb * 32 + kb] = red[0] | red[1] | red[2] | red[3];
  }
}

// ---------------- GEMM core: C(128x128) = A * B^T, BK=64 --------------------
// Single-buffered (proven structure), BK doubled 32->64: halves the
// barrier+drain count (the m97 ~200cyc/step stall). LDS 32KB still allows
// the grid-limited 3 blocks/CU (m132's BK=128 regression was 64KB -> 2).
__device__ __forceinline__ void gemm128_core(
    const unsigned short* __restrict__ A, const unsigned short* __restrict__ Bw,
    int m0, int n0, unsigned short* As, unsigned short* Bs, f32x4 acc[4][4]) {
  const int t = threadIdx.x;
  const int lane = t & 63;
  const int r = lane & 15, g = lane >> 4;
  const int wr = (t >> 6) >> 1, wc = (t >> 6) & 1;
  for (int k0 = 0; k0 < HID; k0 += 64) {
#pragma unroll
    for (int i = 0; i < 4; ++i) {
      int c = i * 256 + t;           // 1024 16B-chunks per 128x64 tile
      int row = c >> 3, sl = (c & 7) << 3;
      load_lds16(A + (size_t)(m0 + row) * HID + k0 + sl, As + c * 8);
      load_lds16(Bw + (size_t)(n0 + row) * HID + k0 + sl, Bs + c * 8);
    }
    __syncthreads();
#pragma unroll
    for (int kk = 0; kk < 2; ++kk) {
      bf16x8 af[4], bf[4];
#pragma unroll
      for (int mt = 0; mt < 4; ++mt)
        af[mt] = *reinterpret_cast<const bf16x8*>(
            As + (wr * 64 + mt * 16 + r) * 64 + kk * 32 + g * 8);
#pragma unroll
      for (int nt = 0; nt < 4; ++nt)
        bf[nt] = *reinterpret_cast<const bf16x8*>(
            Bs + (wc * 64 + nt * 16 + r) * 64 + kk * 32 + g * 8);
#pragma unroll
      for (int mt = 0; mt < 4; ++mt)
#pragma unroll
        for (int nt = 0; nt < 4; ++nt)
          acc[mt][nt] = __builtin_amdgcn_mfma_f32_16x16x32_bf16(af[mt], bf[nt], acc[mt][nt], 0, 0, 0);
    }
    __syncthreads();
  }
}

// ---------------- fused QKV projection (N = 3072, z = n>>10) -----------------
// Q output pre-scaled by 0.125*log2(e) (attention scale + exp2 folding).
__global__ __launch_bounds__(256) void gemm_qkv(
    const unsigned short* __restrict__ xb, const unsigned short* __restrict__ wb,
    const float* __restrict__ bq, const float* __restrict__ bk,
    const float* __restrict__ bv, unsigned short* __restrict__ Qd,
    unsigned short* __restrict__ Kd, unsigned short* __restrict__ Vt) {
  __shared__ __align__(16) unsigned short As[128 * 64];
  __shared__ __align__(16) unsigned short Bs[128 * 64];
  const int m0 = blockIdx.y * 128, n0 = blockIdx.x * 128;
  const int z = n0 >> 10;  // 128-tile never straddles a weight boundary
  f32x4 zv = {0.f, 0.f, 0.f, 0.f};
  f32x4 acc[4][4];
#pragma unroll
  for (int a = 0; a < 4; ++a)
#pragma unroll
    for (int c = 0; c < 4; ++c) acc[a][c] = zv;
  gemm128_core(xb, wb, m0, n0, As, Bs, acc);
  const int t = threadIdx.x, lane = t & 63;
  const int r = lane & 15, g = lane >> 4;
  const int wr = (t >> 6) >> 1, wc = (t >> 6) & 1;
  const float* bias = (z == 0) ? bq : (z == 1) ? bk : bv;
  const float scl = (z == 0) ? 0.125f * 1.44269504f : 1.0f;
#pragma unroll
  for (int nt = 0; nt < 4; ++nt) {
    int n = n0 + wc * 64 + nt * 16 + r;
    int nn = n & 1023;
    float bb = bias[nn];
    int h = nn >> 6, d = nn & 63;
#pragma unroll
    for (int mt = 0; mt < 4; ++mt) {
#pragma unroll
      for (int i = 0; i < 4; ++i) {
        int m = m0 + wr * 64 + mt * 16 + g * 4 + i;
        int b = m >> 11, s = m & 2047;
        int bh = b * NH + h;
        unsigned short val = f2bf((acc[mt][nt][i] + bb) * scl);
        if (z == 0)      Qd[((size_t)bh * SEQ + s) * HD + d] = val;
        else if (z == 1) Kd[((size_t)bh * SEQ + s) * HD + d] = val;
        else             Vt[((size_t)bh * HD + d) * SEQ + s] = val;
      }
    }
  }
}

// ---------------- output projection: fp32 out + bias ------------------------
__global__ __launch_bounds__(256) void gemm_out(
    const unsigned short* __restrict__ Ob, const unsigned short* __restrict__ Wob,
    const float* __restrict__ bo, float* __restrict__ out) {
  __shared__ __align__(16) unsigned short As[128 * 64];
  __shared__ __align__(16) unsigned short Bs[128 * 64];
  const int m0 = blockIdx.y * 128, n0 = blockIdx.x * 128;
  f32x4 zv = {0.f, 0.f, 0.f, 0.f};
  f32x4 acc[4][4];
#pragma unroll
  for (int a = 0; a < 4; ++a)
#pragma unroll
    for (int c = 0; c < 4; ++c) acc[a][c] = zv;
  gemm128_core(Ob, Wob, m0, n0, As, Bs, acc);
  const int t = threadIdx.x, lane = t & 63;
  const int r = lane & 15, g = lane >> 4;
  const int wr = (t >> 6) >> 1, wc = (t >> 6) & 1;
#pragma unroll
  for (int nt = 0; nt < 4; ++nt) {
    int n = n0 + wc * 64 + nt * 16 + r;
    float bb = bo[n];
#pragma unroll
    for (int mt = 0; mt < 4; ++mt) {
#pragma unroll
      for (int i = 0; i < 4; ++i) {
        int m = m0 + wr * 64 + mt * 16 + g * 4 + i;
        out[(size_t)m * HID + n] = acc[mt][nt][i] + bb;
      }
    }
  }
}

// ---------------- flash attention v10b: v10 + permlane cross-lane max -------
// flat grid 512; XCD-clustered decode (FETCH 70 -> 12.4 MB measured r12).
// 256 threads = 4 waves; wave owns 32 queries (swapped-QK, 32x32x16 MFMA,
// in-register softmax, exp2 via bare v_exp_f32). 4-buffer LDS ring, counted
// vmcnt(8), one s_barrier per tile. Cross-lane max via permlane32_swap
// (VALU, ~4cyc) instead of shfl_xor (ds_bpermute, ~30cyc serial-path).
__global__ __launch_bounds__(256, 2) void flash_attn(
    const unsigned short* __restrict__ Q, const unsigned short* __restrict__ K,
    const unsigned short* __restrict__ Vt, const int* __restrict__ map,
    const int* __restrict__ mask, unsigned short* __restrict__ O) {
  __shared__ __align__(16) unsigned short Ks[4][64][64];
  __shared__ __align__(16) unsigned short Vs[4][64][64];
  const int wg = blockIdx.x;
  const int qb = (wg >> 3) & 15;
  const int bh = (wg & 7) | ((wg >> 7) << 3);
  const int t = threadIdx.x;
  const int lane = t & 63, wave = t >> 6;
  const int q = lane & 31, hi = lane >> 5;
  const int q0w = qb * 128 + wave * 32;
  const unsigned short* Qb = Q + (size_t)bh * SEQ * HD;
  const unsigned short* Kb = K + (size_t)bh * SEQ * HD;
  const unsigned short* Vb = Vt + (size_t)bh * HD * SEQ;

  // Q as B-operand fragments: lane holds Q[q0w+q][dd*16 + hi*8 + j]
  bf16x8 qfr[4];
#pragma unroll
  for (int dd = 0; dd < 4; ++dd)
    qfr[dd] = *reinterpret_cast<const bf16x8*>(
        Qb + (size_t)(q0w + q) * HD + dd * 16 + hi * 8);

  // mask tile map for this q-row, as a wave-uniform bitmask (bit kb>>6)
  const unsigned long long mapmask =
      __ballot(map[(q0w >> 6) * 32 + (lane & 31)] != 0);
  const int* maskrow = mask + (size_t)(q0w + q) * SEQ;

  bf16x8 onesf;
#pragma unroll
  for (int j = 0; j < 8; ++j) onesf[j] = (short)0x3F80;  // bf16 1.0

  f32x16 zv16 = {0.f};
  f32x16 oacc[2];
  oacc[0] = zv16; oacc[1] = zv16;
  float mrun = -1e30f, lrun = 0.f;

  // per-lane LDS fragment byte offsets (shared by K and V reads):
  // frag(row = blk*32 + q, slot = j*2 + hi) at region + blk*4096 + offs[j]
  unsigned offs[4];
#pragma unroll
  for (int j = 0; j < 4; ++j)
    offs[j] = q * 128 + ((((j << 1) | hi) ^ (q & 7)) << 4);
  const char* kB = (const char*)Ks;
  const char* vB = (const char*)Vs;

  // staging: 256 threads cover rows {srow, 32+srow} x 8 16B-slots; source
  // column pre-swizzled (inverse of read swizzle), LDS dest linear.
  const int srow = t >> 3;
  const int sslot = t & 7;
  const int c0 = sslot ^ (srow & 7);
  const unsigned short* kp0 = Kb + (size_t)srow * HD + c0 * 8;
  const unsigned short* kp1 = Kb + (size_t)(32 + srow) * HD + c0 * 8;
  const unsigned short* vp0 = Vb + (size_t)srow * SEQ + c0 * 8;
  const unsigned short* vp1 = Vb + (size_t)(32 + srow) * SEQ + c0 * 8;
  unsigned short* ldK0 = &Ks[0][srow][sslot * 8];
  unsigned short* ldK1 = &Ks[0][32 + srow][sslot * 8];
  unsigned short* ldV0 = &Vs[0][srow][sslot * 8];
  unsigned short* ldV1 = &Vs[0][32 + srow][sslot * 8];
  int sbuf = 0;  // next staging buffer (STAGE called once per tile, in order)

#define STAGE() do {                                                        \
    load_lds16(kp0, (char*)ldK0 + sbuf * 8192);                             \
    load_lds16(kp1, (char*)ldK1 + sbuf * 8192);                             \
    load_lds16(vp0, (char*)ldV0 + sbuf * 8192);                             \
    load_lds16(vp1, (char*)ldV1 + sbuf * 8192);                             \
    kp0 += 64 * HD; kp1 += 64 * HD; vp0 += 64; vp1 += 64;                   \
    sbuf = (sbuf + 1) & 3;                                                  \
  } while (0)

// one K-tile: QK^T -> in-place softmax (exp2) -> pack -> PV (+row-sum MFMA)
#define TILE(buf, kb_t) do {                                                \
    f32x16 s0 = zv16, s1 = zv16;                                            \
    __builtin_amdgcn_s_setprio(1);                                          \
    _Pragma("unroll")                                                       \
    for (int dd = 0; dd < 4; ++dd) {                                        \
      bf16x8 kf0 = *(const bf16x8*)(kB + ((buf) * 8192) + offs[dd]);        \
      bf16x8 kf1 = *(const bf16x8*)(kB + ((buf) * 8192 + 4096) + offs[dd]); \
      s0 = __builtin_amdgcn_mfma_f32_32x32x16_bf16(kf0, qfr[dd], s0, 0, 0, 0);\
      s1 = __builtin_amdgcn_mfma_f32_32x32x16_bf16(kf1, qfr[dd], s1, 0, 0, 0);\
    }                                                                       \
    __builtin_amdgcn_s_setprio(0);                                          \
    if ((mapmask >> ((kb_t) >> 6)) & 1) {                                   \
      _Pragma("unroll")                                                     \
      for (int rg = 0; rg < 16; ++rg) {                                     \
        int kl = (rg & 3) + 8 * (rg >> 2) + 4 * hi;                         \
        if (maskrow[(kb_t) + kl] == 0)      s0[rg] = -__builtin_inff();     \
        if (maskrow[(kb_t) + 32 + kl] == 0) s1[rg] = -__builtin_inff();     \
      }                                                                     \
    }                                                                       \
    float t16[16];                                                          \
    _Pragma("unroll")                                                       \
    for (int j = 0; j < 16; ++j) t16[j] = fmaxf(s0[j], s1[j]);              \
    float t4[4];                                                            \
    _Pragma("unroll")                                                       \
    for (int j = 0; j < 4; ++j)                                             \
      t4[j] = fmaxf(fmaxf(t16[j], t16[j + 4]), fmaxf(t16[j + 8], t16[j + 12]));\
    float pmax = fmaxf(fmaxf(t4[0], t4[1]), fmaxf(t4[2], t4[3]));           \
    {                                                                       \
      u32x2 pm2 = __builtin_amdgcn_permlane32_swap(                         \
          __float_as_uint(pmax), __float_as_uint(pmax), false, false);      \
      pmax = fmaxf(__uint_as_float(pm2[0]), __uint_as_float(pm2[1]));       \
    }                                                                       \
    if (!__all(pmax <= mrun + 11.5f)) {                                     \
      float mnew = fmaxf(mrun, pmax);                                       \
      float corr = fexp2(mrun - mnew);                                      \
      mrun = mnew;                                                          \
      lrun *= corr;                                                         \
      _Pragma("unroll")                                                     \
      for (int dh = 0; dh < 2; ++dh)                                        \
        _Pragma("unroll")                                                   \
        for (int rg = 0; rg < 16; ++rg) oacc[dh][rg] *= corr;               \
    }                                                                       \
    _Pragma("unroll")                                                       \
    for (int rg = 0; rg < 16; ++rg) {                                       \
      s0[rg] = fexp2(s0[rg] - mrun);                                        \
      s1[rg] = fexp2(s1[rg] - mrun);                                        \
    }                                                                       \
    bf16x8 pfrag[4];                                                        \
    _Pragma("unroll")                                                       \
    for (int f = 0; f < 4; ++f) {  /* f = ks*2 + half */                    \
      const f32x16& sk = (f >> 1) ? s1 : s0;                                \
      int b0 = (f & 1) * 8;                                                 \
      unsigned w0 = cvtpk(sk[b0 + 0], sk[b0 + 1]);                          \
      unsigned w1 = cvtpk(sk[b0 + 2], sk[b0 + 3]);                          \
      unsigned w2 = cvtpk(sk[b0 + 4], sk[b0 + 5]);                          \
      unsigned w3 = cvtpk(sk[b0 + 6], sk[b0 + 7]);                          \
      u32x2 s02 = __builtin_amdgcn_permlane32_swap(w0, w2, false, false);   \
      u32x2 s13 = __builtin_amdgcn_permlane32_swap(w1, w3, false, false);   \
      union { unsigned u[4]; bf16x8 v; } fr;                                \
      fr.u[0] = s02[0]; fr.u[1] = s13[0]; fr.u[2] = s02[1]; fr.u[3] = s13[1];\
      pfrag[f] = fr.v;                                                      \
    }                                                                       \
    f32x16 lacc = zv16;                                                     \
    __builtin_amdgcn_s_setprio(1);                                          \
    _Pragma("unroll")                                                       \
    for (int f = 0; f < 4; ++f)                                             \
      lacc = __builtin_amdgcn_mfma_f32_32x32x16_bf16(onesf, pfrag[f], lacc, \
                                                     0, 0, 0);              \
    _Pragma("unroll")                                                       \
    for (int f = 0; f < 4; ++f) {                                           \
      bf16x8 vf0 = *(const bf16x8*)(vB + ((buf) * 8192) + offs[f]);         \
      bf16x8 vf1 = *(const bf16x8*)(vB + ((buf) * 8192 + 4096) + offs[f]);  \
      oacc[0] = __builtin_amdgcn_mfma_f32_32x32x16_bf16(vf0, pfrag[f],      \
                                                        oacc[0], 0, 0, 0);  \
      oacc[1] = __builtin_amdgcn_mfma_f32_32x32x16_bf16(vf1, pfrag[f],      \
                                                        oacc[1], 0, 0, 0);  \
    }                                                                       \
    __builtin_amdgcn_s_setprio(0);                                          \
    lrun += lacc[0];                                                        \
  } while (0)

// counted-vmcnt iteration: stage tile t+2, wait tile t done (leave 8 loads
// in flight), rendezvous, compute tile t.  VM must be a literal.
#define ITER(bufc, tv, DO_STAGE, VM) do {                                   \
    if (DO_STAGE) STAGE();                                                  \
    asm volatile("s_waitcnt vmcnt(" #VM ")" ::: "memory");                  \
    __builtin_amdgcn_s_barrier();                                           \
    TILE(bufc, (tv) * 64);                                                  \
  } while (0)

  STAGE();  // tile 0
  STAGE();  // tile 1

  for (int tt = 0; tt < 28; tt += 4) {
    ITER(0, tt + 0, 1, 8);
    ITER(1, tt + 1, 1, 8);
    ITER(2, tt + 2, 1, 8);
    ITER(3, tt + 3, 1, 8);
  }
  ITER(0, 28, 1, 8);   // stages tile 30
  ITER(1, 29, 1, 8);   // stages tile 31
  ITER(2, 30, 0, 4);
  ITER(3, 31, 0, 0);

  const float rl = 1.0f / lrun;
  const int b = bh >> 4, h = bh & 15;
  unsigned short* orow = O + (size_t)(b * SEQ + q0w + q) * HID + h * HD;
#pragma unroll
  for (int dh = 0; dh < 2; ++dh)
#pragma unroll
    for (int r2 = 0; r2 < 4; ++r2) {
      float v0 = oacc[dh][r2 * 4 + 0] * rl;
      float v1 = oacc[dh][r2 * 4 + 1] * rl;
      float v2 = oacc[dh][r2 * 4 + 2] * rl;
      float v3 = oacc[dh][r2 * 4 + 3] * rl;
      u32x2 pk;
      pk[0] = (unsigned)f2bf(v0) | ((unsigned)f2bf(v1) << 16);
      pk[1] = (unsigned)f2bf(v2) | ((unsigned)f2bf(v3) << 16);
      *reinterpret_cast<u32x2*>(orow + dh * 32 + r2 * 8 + hi * 4) = pk;
    }
#undef STAGE
#undef TILE
#undef ITER
}

// ---------------- launch -----------------------------------------------------
extern "C" void kernel_launch(void* const* d_in, const int* in_sizes, int n_in,
                              void* d_out, int out_size, void* d_ws, size_t ws_size,
                              hipStream_t stream) {
  const float* x    = (const float*)d_in[0];
  const int*   mask = (const int*)d_in[1];
  const float* Wq   = (const float*)d_in[2];
  const float* bq   = (const float*)d_in[3];
  const float* Wk   = (const float*)d_in[4];
  const float* bk   = (const float*)d_in[5];
  const float* Wv   = (const float*)d_in[6];
  const float* bv   = (const float*)d_in[7];
  const float* Wo   = (const float*)d_in[8];
  const float* bo   = (const float*)d_in[9];
  float* out = (float*)d_out;

  unsigned short* ws = (unsigned short*)d_ws;
  unsigned short* xb = ws;                      // 4194304 bf16
  unsigned short* wb = ws + 4194304;            // 4 x 1048576 (Wq,Wk,Wv,Wo)
  unsigned short* Qd = ws + 8388608;            // [32][2048][64] (pre-scaled)
  unsigned short* Kd = ws + 12582912;           // [32][2048][64]
  unsigned short* Vt = ws + 16777216;           // [32][64][2048]
  unsigned short* Ob = ws + 20971520;           // [4096][1024]
  int* map = (int*)(ws + 25165824);             // [32][32]

  convert_and_mask<<<5120, 256, 0, stream>>>(x, Wq, Wk, Wv, Wo, mask, ws, map);
  gemm_qkv<<<dim3(24, 32), 256, 0, stream>>>(xb, wb, bq, bk, bv, Qd, Kd, Vt);
  flash_attn<<<512, 256, 0, stream>>>(Qd, Kd, Vt, map, mask, Ob);
  gemm_out<<<dim3(8, 32), 256, 0, stream>>>(Ob, wb + 3 * 1048576, bo, out);
}

// Round 17
// 126.585 us; speedup vs baseline: 1.1966x; 1.1966x over previous
//
#include <hip/hip_runtime.h>
#include <stdint.h>
#include <stddef.h>

#define SEQ 2048
#define NH 16
#define HD 64
#define NB 2
#define HID 1024

typedef short bf16x8 __attribute__((ext_vector_type(8)));
typedef unsigned short ushort8 __attribute__((ext_vector_type(8)));
typedef float f32x4 __attribute__((ext_vector_type(4)));
typedef float f32x16 __attribute__((ext_vector_type(16)));
typedef unsigned u32x2 __attribute__((ext_vector_type(2)));

__device__ __forceinline__ unsigned short f2bf(float f) {
  unsigned u = __float_as_uint(f);
  u += 0x7fffu + ((u >> 16) & 1u);
  return (unsigned short)(u >> 16);
}

__device__ __forceinline__ unsigned cvtpk(float lo, float hi) {
  unsigned d;
  asm("v_cvt_pk_bf16_f32 %0, %1, %2" : "=v"(d) : "v"(lo), "v"(hi));
  return d;
}

// bare v_exp_f32 (2^x): exp2f() lowers to the slow precise OCML path (r7 lesson)
__device__ __forceinline__ float fexp2(float x) {
  float d;
  asm("v_exp_f32 %0, %1" : "=v"(d) : "v"(x));
  return d;
}

__device__ __forceinline__ void load_lds16(const void* g, void* l) {
  __builtin_amdgcn_global_load_lds(
      (const __attribute__((address_space(1))) unsigned int*)g,
      (__attribute__((address_space(3))) unsigned int*)l, 16, 0, 0);
}

// ---------------- fused: fp32->bf16 convert (x + 4 weights) & mask map ------
// blocks [0,4096): convert 8 floats/thread (4096*256*8 = 8388608 elements,
// exactly x + 4 weights); blocks [4096,5120): mask -> 64x64 any-zero map.
__global__ __launch_bounds__(256) void convert_and_mask(
    const float* __restrict__ x, const float* __restrict__ wq,
    const float* __restrict__ wk, const float* __restrict__ wv,
    const float* __restrict__ wo, const int* __restrict__ mask,
    unsigned short* __restrict__ dst, int* __restrict__ map) {
  const int bid = blockIdx.x;
  if (bid < 4096) {
    long i = ((long)bid * 256 + threadIdx.x) * 8;
    const float* src; long off;
    if (i < 4194304L)      { src = x;  off = i; }
    else if (i < 5242880L) { src = wq; off = i - 4194304L; }
    else if (i < 6291456L) { src = wk; off = i - 5242880L; }
    else if (i < 7340032L) { src = wv; off = i - 6291456L; }
    else                   { src = wo; off = i - 7340032L; }
    float4 a = *reinterpret_cast<const float4*>(src + off);
    float4 b = *reinterpret_cast<const float4*>(src + off + 4);
    ushort8 o;
    o[0] = f2bf(a.x); o[1] = f2bf(a.y); o[2] = f2bf(a.z); o[3] = f2bf(a.w);
    o[4] = f2bf(b.x); o[5] = f2bf(b.y); o[6] = f2bf(b.z); o[7] = f2bf(b.w);
    *reinterpret_cast<ushort8*>(dst + i) = o;
  } else {
    const int b2 = bid - 4096;
    const int qb = b2 >> 5, kb = b2 & 31;
    int bad = 0;
    for (int i = threadIdx.x; i < 4096; i += 256) {
      int qq = i >> 6, kk = i & 63;
      bad |= (mask[(size_t)(qb * 64 + qq) * SEQ + kb * 64 + kk] == 0);
    }
    __shared__ int red[4];
    unsigned long long any = __ballot(bad);
    if ((threadIdx.x & 63) == 0) red[threadIdx.x >> 6] = (any != 0ULL);
    __syncthreads();
    if (threadIdx.x == 0) map[qb * 32 + kb] = red[0] | red[1] | red[2] | red[3];
  }
}

// ---------------- m97-structure GEMM core: C(128x128) = A * B^T --------------
// BK=32, single-buffered — the proven r5-r15 version (~35us qkv). BK=64 (r16)
// regressed 2.5x: 128B LDS row stride = same-bank for all 16 rows (G4 trap).
__device__ __forceinline__ void gemm128_core(
    const unsigned short* __restrict__ A, const unsigned short* __restrict__ Bw,
    int m0, int n0, unsigned short* As, unsigned short* Bs, f32x4 acc[4][4]) {
  const int t = threadIdx.x;
  const int lane = t & 63;
  const int r = lane & 15, g = lane >> 4;
  const int wr = (t >> 6) >> 1, wc = (t >> 6) & 1;
  for (int k0 = 0; k0 < HID; k0 += 32) {
#pragma unroll
    for (int i = 0; i < 2; ++i) {
      int c = i * 256 + t;           // 512 16B-chunks per 128x32 tile
      int row = c >> 2, sl = (c & 3) << 3;
      load_lds16(A + (size_t)(m0 + row) * HID + k0 + sl, As + c * 8);
      load_lds16(Bw + (size_t)(n0 + row) * HID + k0 + sl, Bs + c * 8);
    }
    __syncthreads();
    bf16x8 af[4], bf[4];
#pragma unroll
    for (int mt = 0; mt < 4; ++mt)
      af[mt] = *reinterpret_cast<const bf16x8*>(As + (wr * 64 + mt * 16 + r) * 32 + g * 8);
#pragma unroll
    for (int nt = 0; nt < 4; ++nt)
      bf[nt] = *reinterpret_cast<const bf16x8*>(Bs + (wc * 64 + nt * 16 + r) * 32 + g * 8);
#pragma unroll
    for (int mt = 0; mt < 4; ++mt)
#pragma unroll
      for (int nt = 0; nt < 4; ++nt)
        acc[mt][nt] = __builtin_amdgcn_mfma_f32_16x16x32_bf16(af[mt], bf[nt], acc[mt][nt], 0, 0, 0);
    __syncthreads();
  }
}

// ---------------- fused QKV projection (N = 3072, z = n>>10) -----------------
// Q output pre-scaled by 0.125*log2(e) (attention scale + exp2 folding).
__global__ __launch_bounds__(256) void gemm_qkv(
    const unsigned short* __restrict__ xb, const unsigned short* __restrict__ wb,
    const float* __restrict__ bq, const float* __restrict__ bk,
    const float* __restrict__ bv, unsigned short* __restrict__ Qd,
    unsigned short* __restrict__ Kd, unsigned short* __restrict__ Vt) {
  __shared__ __align__(16) unsigned short As[128 * 32];
  __shared__ __align__(16) unsigned short Bs[128 * 32];
  const int m0 = blockIdx.y * 128, n0 = blockIdx.x * 128;
  const int z = n0 >> 10;  // 128-tile never straddles a weight boundary
  f32x4 zv = {0.f, 0.f, 0.f, 0.f};
  f32x4 acc[4][4];
#pragma unroll
  for (int a = 0; a < 4; ++a)
#pragma unroll
    for (int c = 0; c < 4; ++c) acc[a][c] = zv;
  gemm128_core(xb, wb, m0, n0, As, Bs, acc);
  const int t = threadIdx.x, lane = t & 63;
  const int r = lane & 15, g = lane >> 4;
  const int wr = (t >> 6) >> 1, wc = (t >> 6) & 1;
  const float* bias = (z == 0) ? bq : (z == 1) ? bk : bv;
  const float scl = (z == 0) ? 0.125f * 1.44269504f : 1.0f;
#pragma unroll
  for (int nt = 0; nt < 4; ++nt) {
    int n = n0 + wc * 64 + nt * 16 + r;
    int nn = n & 1023;
    float bb = bias[nn];
    int h = nn >> 6, d = nn & 63;
#pragma unroll
    for (int mt = 0; mt < 4; ++mt) {
#pragma unroll
      for (int i = 0; i < 4; ++i) {
        int m = m0 + wr * 64 + mt * 16 + g * 4 + i;
        int b = m >> 11, s = m & 2047;
        int bh = b * NH + h;
        unsigned short val = f2bf((acc[mt][nt][i] + bb) * scl);
        if (z == 0)      Qd[((size_t)bh * SEQ + s) * HD + d] = val;
        else if (z == 1) Kd[((size_t)bh * SEQ + s) * HD + d] = val;
        else             Vt[((size_t)bh * HD + d) * SEQ + s] = val;
      }
    }
  }
}

// ---------------- output projection: fp32 out + bias ------------------------
__global__ __launch_bounds__(256) void gemm_out(
    const unsigned short* __restrict__ Ob, const unsigned short* __restrict__ Wob,
    const float* __restrict__ bo, float* __restrict__ out) {
  __shared__ __align__(16) unsigned short As[128 * 32];
  __shared__ __align__(16) unsigned short Bs[128 * 32];
  const int m0 = blockIdx.y * 128, n0 = blockIdx.x * 128;
  f32x4 zv = {0.f, 0.f, 0.f, 0.f};
  f32x4 acc[4][4];
#pragma unroll
  for (int a = 0; a < 4; ++a)
#pragma unroll
    for (int c = 0; c < 4; ++c) acc[a][c] = zv;
  gemm128_core(Ob, Wob, m0, n0, As, Bs, acc);
  const int t = threadIdx.x, lane = t & 63;
  const int r = lane & 15, g = lane >> 4;
  const int wr = (t >> 6) >> 1, wc = (t >> 6) & 1;
#pragma unroll
  for (int nt = 0; nt < 4; ++nt) {
    int n = n0 + wc * 64 + nt * 16 + r;
    float bb = bo[n];
#pragma unroll
    for (int mt = 0; mt < 4; ++mt) {
#pragma unroll
      for (int i = 0; i < 4; ++i) {
        int m = m0 + wr * 64 + mt * 16 + g * 4 + i;
        out[(size_t)m * HID + n] = acc[mt][nt][i] + bb;
      }
    }
  }
}

// ---------------- flash attention v10b: v10 + permlane cross-lane max -------
// flat grid 512; XCD-clustered decode (FETCH 70 -> 12.4 MB measured r12).
// 256 threads = 4 waves; wave owns 32 queries (swapped-QK, 32x32x16 MFMA,
// in-register softmax, exp2 via bare v_exp_f32). 4-buffer LDS ring, counted
// vmcnt(8), one s_barrier per tile. Cross-lane max via permlane32_swap.
__global__ __launch_bounds__(256, 2) void flash_attn(
    const unsigned short* __restrict__ Q, const unsigned short* __restrict__ K,
    const unsigned short* __restrict__ Vt, const int* __restrict__ map,
    const int* __restrict__ mask, unsigned short* __restrict__ O) {
  __shared__ __align__(16) unsigned short Ks[4][64][64];
  __shared__ __align__(16) unsigned short Vs[4][64][64];
  const int wg = blockIdx.x;
  const int qb = (wg >> 3) & 15;
  const int bh = (wg & 7) | ((wg >> 7) << 3);
  const int t = threadIdx.x;
  const int lane = t & 63, wave = t >> 6;
  const int q = lane & 31, hi = lane >> 5;
  const int q0w = qb * 128 + wave * 32;
  const unsigned short* Qb = Q + (size_t)bh * SEQ * HD;
  const unsigned short* Kb = K + (size_t)bh * SEQ * HD;
  const unsigned short* Vb = Vt + (size_t)bh * HD * SEQ;

  // Q as B-operand fragments: lane holds Q[q0w+q][dd*16 + hi*8 + j]
  bf16x8 qfr[4];
#pragma unroll
  for (int dd = 0; dd < 4; ++dd)
    qfr[dd] = *reinterpret_cast<const bf16x8*>(
        Qb + (size_t)(q0w + q) * HD + dd * 16 + hi * 8);

  // mask tile map for this q-row, as a wave-uniform bitmask (bit kb>>6)
  const unsigned long long mapmask =
      __ballot(map[(q0w >> 6) * 32 + (lane & 31)] != 0);
  const int* maskrow = mask + (size_t)(q0w + q) * SEQ;

  bf16x8 onesf;
#pragma unroll
  for (int j = 0; j < 8; ++j) onesf[j] = (short)0x3F80;  // bf16 1.0

  f32x16 zv16 = {0.f};
  f32x16 oacc[2];
  oacc[0] = zv16; oacc[1] = zv16;
  float mrun = -1e30f, lrun = 0.f;

  // per-lane LDS fragment byte offsets (shared by K and V reads):
  // frag(row = blk*32 + q, slot = j*2 + hi) at region + blk*4096 + offs[j]
  unsigned offs[4];
#pragma unroll
  for (int j = 0; j < 4; ++j)
    offs[j] = q * 128 + ((((j << 1) | hi) ^ (q & 7)) << 4);
  const char* kB = (const char*)Ks;
  const char* vB = (const char*)Vs;

  // staging: 256 threads cover rows {srow, 32+srow} x 8 16B-slots; source
  // column pre-swizzled (inverse of read swizzle), LDS dest linear.
  const int srow = t >> 3;
  const int sslot = t & 7;
  const int c0 = sslot ^ (srow & 7);
  const unsigned short* kp0 = Kb + (size_t)srow * HD + c0 * 8;
  const unsigned short* kp1 = Kb + (size_t)(32 + srow) * HD + c0 * 8;
  const unsigned short* vp0 = Vb + (size_t)srow * SEQ + c0 * 8;
  const unsigned short* vp1 = Vb + (size_t)(32 + srow) * SEQ + c0 * 8;
  unsigned short* ldK0 = &Ks[0][srow][sslot * 8];
  unsigned short* ldK1 = &Ks[0][32 + srow][sslot * 8];
  unsigned short* ldV0 = &Vs[0][srow][sslot * 8];
  unsigned short* ldV1 = &Vs[0][32 + srow][sslot * 8];
  int sbuf = 0;  // next staging buffer (STAGE called once per tile, in order)

#define STAGE() do {                                                        \
    load_lds16(kp0, (char*)ldK0 + sbuf * 8192);                             \
    load_lds16(kp1, (char*)ldK1 + sbuf * 8192);                             \
    load_lds16(vp0, (char*)ldV0 + sbuf * 8192);                             \
    load_lds16(vp1, (char*)ldV1 + sbuf * 8192);                             \
    kp0 += 64 * HD; kp1 += 64 * HD; vp0 += 64; vp1 += 64;                   \
    sbuf = (sbuf + 1) & 3;                                                  \
  } while (0)

// one K-tile: QK^T -> in-place softmax (exp2) -> pack -> PV (+row-sum MFMA)
#define TILE(buf, kb_t) do {                                                \
    f32x16 s0 = zv16, s1 = zv16;                                            \
    __builtin_amdgcn_s_setprio(1);                                          \
    _Pragma("unroll")                                                       \
    for (int dd = 0; dd < 4; ++dd) {                                        \
      bf16x8 kf0 = *(const bf16x8*)(kB + ((buf) * 8192) + offs[dd]);        \
      bf16x8 kf1 = *(const bf16x8*)(kB + ((buf) * 8192 + 4096) + offs[dd]); \
      s0 = __builtin_amdgcn_mfma_f32_32x32x16_bf16(kf0, qfr[dd], s0, 0, 0, 0);\
      s1 = __builtin_amdgcn_mfma_f32_32x32x16_bf16(kf1, qfr[dd], s1, 0, 0, 0);\
    }                                                                       \
    __builtin_amdgcn_s_setprio(0);                                          \
    if ((mapmask >> ((kb_t) >> 6)) & 1) {                                   \
      _Pragma("unroll")                                                     \
      for (int rg = 0; rg < 16; ++rg) {                                     \
        int kl = (rg & 3) + 8 * (rg >> 2) + 4 * hi;                         \
        if (maskrow[(kb_t) + kl] == 0)      s0[rg] = -__builtin_inff();     \
        if (maskrow[(kb_t) + 32 + kl] == 0) s1[rg] = -__builtin_inff();     \
      }                                                                     \
    }                                                                       \
    float t16[16];                                                          \
    _Pragma("unroll")                                                       \
    for (int j = 0; j < 16; ++j) t16[j] = fmaxf(s0[j], s1[j]);              \
    float t4[4];                                                            \
    _Pragma("unroll")                                                       \
    for (int j = 0; j < 4; ++j)                                             \
      t4[j] = fmaxf(fmaxf(t16[j], t16[j + 4]), fmaxf(t16[j + 8], t16[j + 12]));\
    float pmax = fmaxf(fmaxf(t4[0], t4[1]), fmaxf(t4[2], t4[3]));           \
    {                                                                       \
      u32x2 pm2 = __builtin_amdgcn_permlane32_swap(                         \
          __float_as_uint(pmax), __float_as_uint(pmax), false, false);      \
      pmax = fmaxf(__uint_as_float(pm2[0]), __uint_as_float(pm2[1]));       \
    }                                                                       \
    if (!__all(pmax <= mrun + 11.5f)) {                                     \
      float mnew = fmaxf(mrun, pmax);                                       \
      float corr = fexp2(mrun - mnew);                                      \
      mrun = mnew;                                                          \
      lrun *= corr;                                                         \
      _Pragma("unroll")                                                     \
      for (int dh = 0; dh < 2; ++dh)                                        \
        _Pragma("unroll")                                                   \
        for (int rg = 0; rg < 16; ++rg) oacc[dh][rg] *= corr;               \
    }                                                                       \
    _Pragma("unroll")                                                       \
    for (int rg = 0; rg < 16; ++rg) {                                       \
      s0[rg] = fexp2(s0[rg] - mrun);                                        \
      s1[rg] = fexp2(s1[rg] - mrun);                                        \
    }                                                                       \
    bf16x8 pfrag[4];                                                        \
    _Pragma("unroll")                                                       \
    for (int f = 0; f < 4; ++f) {  /* f = ks*2 + half */                    \
      const f32x16& sk = (f >> 1) ? s1 : s0;                                \
      int b0 = (f & 1) * 8;                                                 \
      unsigned w0 = cvtpk(sk[b0 + 0], sk[b0 + 1]);                          \
      unsigned w1 = cvtpk(sk[b0 + 2], sk[b0 + 3]);                          \
      unsigned w2 = cvtpk(sk[b0 + 4], sk[b0 + 5]);                          \
      unsigned w3 = cvtpk(sk[b0 + 6], sk[b0 + 7]);                          \
      u32x2 s02 = __builtin_amdgcn_permlane32_swap(w0, w2, false, false);   \
      u32x2 s13 = __builtin_amdgcn_permlane32_swap(w1, w3, false, false);   \
      union { unsigned u[4]; bf16x8 v; } fr;                                \
      fr.u[0] = s02[0]; fr.u[1] = s13[0]; fr.u[2] = s02[1]; fr.u[3] = s13[1];\
      pfrag[f] = fr.v;                                                      \
    }                                                                       \
    f32x16 lacc = zv16;                                                     \
    __builtin_amdgcn_s_setprio(1);                                          \
    _Pragma("unroll")                                                       \
    for (int f = 0; f < 4; ++f)                                             \
      lacc = __builtin_amdgcn_mfma_f32_32x32x16_bf16(onesf, pfrag[f], lacc, \
                                                     0, 0, 0);              \
    _Pragma("unroll")                                                       \
    for (int f = 0; f < 4; ++f) {                                           \
      bf16x8 vf0 = *(const bf16x8*)(vB + ((buf) * 8192) + offs[f]);         \
      bf16x8 vf1 = *(const bf16x8*)(vB + ((buf) * 8192 + 4096) + offs[f]);  \
      oacc[0] = __builtin_amdgcn_mfma_f32_32x32x16_bf16(vf0, pfrag[f],      \
                                                        oacc[0], 0, 0, 0);  \
      oacc[1] = __builtin_amdgcn_mfma_f32_32x32x16_bf16(vf1, pfrag[f],      \
                                                        oacc[1], 0, 0, 0);  \
    }                                                                       \
    __builtin_amdgcn_s_setprio(0);                                          \
    lrun += lacc[0];                                                        \
  } while (0)

// counted-vmcnt iteration: stage tile t+2, wait tile t done (leave 8 loads
// in flight), rendezvous, compute tile t.  VM must be a literal.
#define ITER(bufc, tv, DO_STAGE, VM) do {                                   \
    if (DO_STAGE) STAGE();                                                  \
    asm volatile("s_waitcnt vmcnt(" #VM ")" ::: "memory");                  \
    __builtin_amdgcn_s_barrier();                                           \
    TILE(bufc, (tv) * 64);                                                  \
  } while (0)

  STAGE();  // tile 0
  STAGE();  // tile 1

  for (int tt = 0; tt < 28; tt += 4) {
    ITER(0, tt + 0, 1, 8);
    ITER(1, tt + 1, 1, 8);
    ITER(2, tt + 2, 1, 8);
    ITER(3, tt + 3, 1, 8);
  }
  ITER(0, 28, 1, 8);   // stages tile 30
  ITER(1, 29, 1, 8);   // stages tile 31
  ITER(2, 30, 0, 4);
  ITER(3, 31, 0, 0);

  const float rl = 1.0f / lrun;
  const int b = bh >> 4, h = bh & 15;
  unsigned short* orow = O + (size_t)(b * SEQ + q0w + q) * HID + h * HD;
#pragma unroll
  for (int dh = 0; dh < 2; ++dh)
#pragma unroll
    for (int r2 = 0; r2 < 4; ++r2) {
      float v0 = oacc[dh][r2 * 4 + 0] * rl;
      float v1 = oacc[dh][r2 * 4 + 1] * rl;
      float v2 = oacc[dh][r2 * 4 + 2] * rl;
      float v3 = oacc[dh][r2 * 4 + 3] * rl;
      u32x2 pk;
      pk[0] = (unsigned)f2bf(v0) | ((unsigned)f2bf(v1) << 16);
      pk[1] = (unsigned)f2bf(v2) | ((unsigned)f2bf(v3) << 16);
      *reinterpret_cast<u32x2*>(orow + dh * 32 + r2 * 8 + hi * 4) = pk;
    }
#undef STAGE
#undef TILE
#undef ITER
}

// ---------------- launch -----------------------------------------------------
extern "C" void kernel_launch(void* const* d_in, const int* in_sizes, int n_in,
                              void* d_out, int out_size, void* d_ws, size_t ws_size,
                              hipStream_t stream) {
  const float* x    = (const float*)d_in[0];
  const int*   mask = (const int*)d_in[1];
  const float* Wq   = (const float*)d_in[2];
  const float* bq   = (const float*)d_in[3];
  const float* Wk   = (const float*)d_in[4];
  const float* bk   = (const float*)d_in[5];
  const float* Wv   = (const float*)d_in[6];
  const float* bv   = (const float*)d_in[7];
  const float* Wo   = (const float*)d_in[8];
  const float* bo   = (const float*)d_in[9];
  float* out = (float*)d_out;

  unsigned short* ws = (unsigned short*)d_ws;
  unsigned short* xb = ws;                      // 4194304 bf16
  unsigned short* wb = ws + 4194304;            // 4 x 1048576 (Wq,Wk,Wv,Wo)
  unsigned short* Qd = ws + 8388608;            // [32][2048][64] (pre-scaled)
  unsigned short* Kd = ws + 12582912;           // [32][2048][64]
  unsigned short* Vt = ws + 16777216;           // [32][64][2048]
  unsigned short* Ob = ws + 20971520;           // [4096][1024]
  int* map = (int*)(ws + 25165824);             // [32][32]

  convert_and_mask<<<5120, 256, 0, stream>>>(x, Wq, Wk, Wv, Wo, mask, ws, map);
  gemm_qkv<<<dim3(24, 32), 256, 0, stream>>>(xb, wb, bq, bk, bv, Qd, Kd, Vt);
  flash_attn<<<512, 256, 0, stream>>>(Qd, Kd, Vt, map, mask, Ob);
  gemm_out<<<dim3(8, 32), 256, 0, stream>>>(Ob, wb + 3 * 1048576, bo, out);
}

// Round 18
// 124.995 us; speedup vs baseline: 1.2118x; 1.0127x over previous
//
#include <hip/hip_runtime.h>
#include <stdint.h>
#include <stddef.h>

#define SEQ 2048
#define NH 16
#define HD 64
#define NB 2
#define HID 1024

typedef short bf16x8 __attribute__((ext_vector_type(8)));
typedef unsigned short ushort8 __attribute__((ext_vector_type(8)));
typedef float f32x4 __attribute__((ext_vector_type(4)));
typedef float f32x16 __attribute__((ext_vector_type(16)));
typedef unsigned u32x2 __attribute__((ext_vector_type(2)));

__device__ __forceinline__ unsigned short f2bf(float f) {
  unsigned u = __float_as_uint(f);
  u += 0x7fffu + ((u >> 16) & 1u);
  return (unsigned short)(u >> 16);
}

__device__ __forceinline__ unsigned cvtpk(float lo, float hi) {
  unsigned d;
  asm("v_cvt_pk_bf16_f32 %0, %1, %2" : "=v"(d) : "v"(lo), "v"(hi));
  return d;
}

// bare v_exp_f32 (2^x): exp2f() lowers to the slow precise OCML path (r7 lesson)
__device__ __forceinline__ float fexp2(float x) {
  float d;
  asm("v_exp_f32 %0, %1" : "=v"(d) : "v"(x));
  return d;
}

__device__ __forceinline__ void load_lds16(const void* g, void* l) {
  __builtin_amdgcn_global_load_lds(
      (const __attribute__((address_space(1))) unsigned int*)g,
      (__attribute__((address_space(3))) unsigned int*)l, 16, 0, 0);
}

// ---------------- fused: fp32->bf16 convert (x + 4 weights) & mask map ------
// blocks [0,4096): convert 8 floats/thread (4096*256*8 = 8388608 elements,
// exactly x + 4 weights); blocks [4096,5120): mask -> 64x64 any-zero map.
__global__ __launch_bounds__(256) void convert_and_mask(
    const float* __restrict__ x, const float* __restrict__ wq,
    const float* __restrict__ wk, const float* __restrict__ wv,
    const float* __restrict__ wo, const int* __restrict__ mask,
    unsigned short* __restrict__ dst, int* __restrict__ map) {
  const int bid = blockIdx.x;
  if (bid < 4096) {
    long i = ((long)bid * 256 + threadIdx.x) * 8;
    const float* src; long off;
    if (i < 4194304L)      { src = x;  off = i; }
    else if (i < 5242880L) { src = wq; off = i - 4194304L; }
    else if (i < 6291456L) { src = wk; off = i - 5242880L; }
    else if (i < 7340032L) { src = wv; off = i - 6291456L; }
    else                   { src = wo; off = i - 7340032L; }
    float4 a = *reinterpret_cast<const float4*>(src + off);
    float4 b = *reinterpret_cast<const float4*>(src + off + 4);
    ushort8 o;
    o[0] = f2bf(a.x); o[1] = f2bf(a.y); o[2] = f2bf(a.z); o[3] = f2bf(a.w);
    o[4] = f2bf(b.x); o[5] = f2bf(b.y); o[6] = f2bf(b.z); o[7] = f2bf(b.w);
    *reinterpret_cast<ushort8*>(dst + i) = o;
  } else {
    const int b2 = bid - 4096;
    const int qb = b2 >> 5, kb = b2 & 31;
    int bad = 0;
    for (int i = threadIdx.x; i < 4096; i += 256) {
      int qq = i >> 6, kk = i & 63;
      bad |= (mask[(size_t)(qb * 64 + qq) * SEQ + kb * 64 + kk] == 0);
    }
    __shared__ int red[4];
    unsigned long long any = __ballot(bad);
    if ((threadIdx.x & 63) == 0) red[threadIdx.x >> 6] = (any != 0ULL);
    __syncthreads();
    if (threadIdx.x == 0) map[qb * 32 + kb] = red[0] | red[1] | red[2] | red[3];
  }
}

// ---------------- m97-structure GEMM core: C(128x128) = A * B^T --------------
// BK=32, single-buffered — the proven r5-r15 version (~35us qkv). BK=64 (r16)
// regressed 2.5x: 128B LDS row stride = same-bank for all 16 rows (G4 trap).
__device__ __forceinline__ void gemm128_core(
    const unsigned short* __restrict__ A, const unsigned short* __restrict__ Bw,
    int m0, int n0, unsigned short* As, unsigned short* Bs, f32x4 acc[4][4]) {
  const int t = threadIdx.x;
  const int lane = t & 63;
  const int r = lane & 15, g = lane >> 4;
  const int wr = (t >> 6) >> 1, wc = (t >> 6) & 1;
  for (int k0 = 0; k0 < HID; k0 += 32) {
#pragma unroll
    for (int i = 0; i < 2; ++i) {
      int c = i * 256 + t;           // 512 16B-chunks per 128x32 tile
      int row = c >> 2, sl = (c & 3) << 3;
      load_lds16(A + (size_t)(m0 + row) * HID + k0 + sl, As + c * 8);
      load_lds16(Bw + (size_t)(n0 + row) * HID + k0 + sl, Bs + c * 8);
    }
    __syncthreads();
    bf16x8 af[4], bf[4];
#pragma unroll
    for (int mt = 0; mt < 4; ++mt)
      af[mt] = *reinterpret_cast<const bf16x8*>(As + (wr * 64 + mt * 16 + r) * 32 + g * 8);
#pragma unroll
    for (int nt = 0; nt < 4; ++nt)
      bf[nt] = *reinterpret_cast<const bf16x8*>(Bs + (wc * 64 + nt * 16 + r) * 32 + g * 8);
#pragma unroll
    for (int mt = 0; mt < 4; ++mt)
#pragma unroll
      for (int nt = 0; nt < 4; ++nt)
        acc[mt][nt] = __builtin_amdgcn_mfma_f32_16x16x32_bf16(af[mt], bf[nt], acc[mt][nt], 0, 0, 0);
    __syncthreads();
  }
}

// ---------------- fused QKV projection (N = 3072, z = n>>10) -----------------
// Q output pre-scaled by 0.125*log2(e) (attention scale + exp2 folding).
__global__ __launch_bounds__(256) void gemm_qkv(
    const unsigned short* __restrict__ xb, const unsigned short* __restrict__ wb,
    const float* __restrict__ bq, const float* __restrict__ bk,
    const float* __restrict__ bv, unsigned short* __restrict__ Qd,
    unsigned short* __restrict__ Kd, unsigned short* __restrict__ Vt) {
  __shared__ __align__(16) unsigned short As[128 * 32];
  __shared__ __align__(16) unsigned short Bs[128 * 32];
  const int m0 = blockIdx.y * 128, n0 = blockIdx.x * 128;
  const int z = n0 >> 10;  // 128-tile never straddles a weight boundary
  f32x4 zv = {0.f, 0.f, 0.f, 0.f};
  f32x4 acc[4][4];
#pragma unroll
  for (int a = 0; a < 4; ++a)
#pragma unroll
    for (int c = 0; c < 4; ++c) acc[a][c] = zv;
  gemm128_core(xb, wb, m0, n0, As, Bs, acc);
  const int t = threadIdx.x, lane = t & 63;
  const int r = lane & 15, g = lane >> 4;
  const int wr = (t >> 6) >> 1, wc = (t >> 6) & 1;
  const float* bias = (z == 0) ? bq : (z == 1) ? bk : bv;
  const float scl = (z == 0) ? 0.125f * 1.44269504f : 1.0f;
#pragma unroll
  for (int nt = 0; nt < 4; ++nt) {
    int n = n0 + wc * 64 + nt * 16 + r;
    int nn = n & 1023;
    float bb = bias[nn];
    int h = nn >> 6, d = nn & 63;
#pragma unroll
    for (int mt = 0; mt < 4; ++mt) {
#pragma unroll
      for (int i = 0; i < 4; ++i) {
        int m = m0 + wr * 64 + mt * 16 + g * 4 + i;
        int b = m >> 11, s = m & 2047;
        int bh = b * NH + h;
        unsigned short val = f2bf((acc[mt][nt][i] + bb) * scl);
        if (z == 0)      Qd[((size_t)bh * SEQ + s) * HD + d] = val;
        else if (z == 1) Kd[((size_t)bh * SEQ + s) * HD + d] = val;
        else             Vt[((size_t)bh * HD + d) * SEQ + s] = val;
      }
    }
  }
}

// ---------------- output projection: 128x64 tile (2x occupancy) -------------
// grid (16,32) = 512 blocks = 2/CU (old 128x128 was 256 blocks = 1/CU =
// 1 wave/SIMD — half the TLP of gemm_qkv on the same latency-bound core).
// 4 waves of 64x32 (acc[4][2]); BK=32 single-buffered.
__global__ __launch_bounds__(256) void gemm_out(
    const unsigned short* __restrict__ Ob, const unsigned short* __restrict__ Wob,
    const float* __restrict__ bo, float* __restrict__ out) {
  __shared__ __align__(16) unsigned short As[128 * 32];
  __shared__ __align__(16) unsigned short Bs[64 * 32];
  const int m0 = blockIdx.y * 128, n0 = blockIdx.x * 64;
  const int t = threadIdx.x, lane = t & 63;
  const int r = lane & 15, g = lane >> 4;
  const int wr = (t >> 6) >> 1, wc = (t >> 6) & 1;
  f32x4 zv = {0.f, 0.f, 0.f, 0.f};
  f32x4 acc[4][2];
#pragma unroll
  for (int a = 0; a < 4; ++a)
#pragma unroll
    for (int c = 0; c < 2; ++c) acc[a][c] = zv;
  for (int k0 = 0; k0 < HID; k0 += 32) {
#pragma unroll
    for (int i = 0; i < 2; ++i) {
      int c = i * 256 + t;           // A: 512 16B-chunks per 128x32 tile
      int row = c >> 2, sl = (c & 3) << 3;
      load_lds16(Ob + (size_t)(m0 + row) * HID + k0 + sl, As + c * 8);
    }
    {
      int c = t;                     // B: 256 16B-chunks per 64x32 tile
      int row = c >> 2, sl = (c & 3) << 3;
      load_lds16(Wob + (size_t)(n0 + row) * HID + k0 + sl, Bs + c * 8);
    }
    __syncthreads();
    bf16x8 af[4], bf[2];
#pragma unroll
    for (int mt = 0; mt < 4; ++mt)
      af[mt] = *reinterpret_cast<const bf16x8*>(As + (wr * 64 + mt * 16 + r) * 32 + g * 8);
#pragma unroll
    for (int nt = 0; nt < 2; ++nt)
      bf[nt] = *reinterpret_cast<const bf16x8*>(Bs + (wc * 32 + nt * 16 + r) * 32 + g * 8);
#pragma unroll
    for (int mt = 0; mt < 4; ++mt)
#pragma unroll
      for (int nt = 0; nt < 2; ++nt)
        acc[mt][nt] = __builtin_amdgcn_mfma_f32_16x16x32_bf16(af[mt], bf[nt], acc[mt][nt], 0, 0, 0);
    __syncthreads();
  }
#pragma unroll
  for (int nt = 0; nt < 2; ++nt) {
    int n = n0 + wc * 32 + nt * 16 + r;
    float bb = bo[n];
#pragma unroll
    for (int mt = 0; mt < 4; ++mt) {
#pragma unroll
      for (int i = 0; i < 4; ++i) {
        int m = m0 + wr * 64 + mt * 16 + g * 4 + i;
        out[(size_t)m * HID + n] = acc[mt][nt][i] + bb;
      }
    }
  }
}

// ---------------- flash attention v10b: v10 + permlane cross-lane max -------
// flat grid 512; XCD-clustered decode (FETCH 70 -> 12.4 MB measured r12).
// 256 threads = 4 waves; wave owns 32 queries (swapped-QK, 32x32x16 MFMA,
// in-register softmax, exp2 via bare v_exp_f32). 4-buffer LDS ring, counted
// vmcnt(8), one s_barrier per tile. Cross-lane max via permlane32_swap.
__global__ __launch_bounds__(256, 2) void flash_attn(
    const unsigned short* __restrict__ Q, const unsigned short* __restrict__ K,
    const unsigned short* __restrict__ Vt, const int* __restrict__ map,
    const int* __restrict__ mask, unsigned short* __restrict__ O) {
  __shared__ __align__(16) unsigned short Ks[4][64][64];
  __shared__ __align__(16) unsigned short Vs[4][64][64];
  const int wg = blockIdx.x;
  const int qb = (wg >> 3) & 15;
  const int bh = (wg & 7) | ((wg >> 7) << 3);
  const int t = threadIdx.x;
  const int lane = t & 63, wave = t >> 6;
  const int q = lane & 31, hi = lane >> 5;
  const int q0w = qb * 128 + wave * 32;
  const unsigned short* Qb = Q + (size_t)bh * SEQ * HD;
  const unsigned short* Kb = K + (size_t)bh * SEQ * HD;
  const unsigned short* Vb = Vt + (size_t)bh * HD * SEQ;

  // Q as B-operand fragments: lane holds Q[q0w+q][dd*16 + hi*8 + j]
  bf16x8 qfr[4];
#pragma unroll
  for (int dd = 0; dd < 4; ++dd)
    qfr[dd] = *reinterpret_cast<const bf16x8*>(
        Qb + (size_t)(q0w + q) * HD + dd * 16 + hi * 8);

  // mask tile map for this q-row, as a wave-uniform bitmask (bit kb>>6)
  const unsigned long long mapmask =
      __ballot(map[(q0w >> 6) * 32 + (lane & 31)] != 0);
  const int* maskrow = mask + (size_t)(q0w + q) * SEQ;

  bf16x8 onesf;
#pragma unroll
  for (int j = 0; j < 8; ++j) onesf[j] = (short)0x3F80;  // bf16 1.0

  f32x16 zv16 = {0.f};
  f32x16 oacc[2];
  oacc[0] = zv16; oacc[1] = zv16;
  float mrun = -1e30f, lrun = 0.f;

  // per-lane LDS fragment byte offsets (shared by K and V reads):
  // frag(row = blk*32 + q, slot = j*2 + hi) at region + blk*4096 + offs[j]
  unsigned offs[4];
#pragma unroll
  for (int j = 0; j < 4; ++j)
    offs[j] = q * 128 + ((((j << 1) | hi) ^ (q & 7)) << 4);
  const char* kB = (const char*)Ks;
  const char* vB = (const char*)Vs;

  // staging: 256 threads cover rows {srow, 32+srow} x 8 16B-slots; source
  // column pre-swizzled (inverse of read swizzle), LDS dest linear.
  const int srow = t >> 3;
  const int sslot = t & 7;
  const int c0 = sslot ^ (srow & 7);
  const unsigned short* kp0 = Kb + (size_t)srow * HD + c0 * 8;
  const unsigned short* kp1 = Kb + (size_t)(32 + srow) * HD + c0 * 8;
  const unsigned short* vp0 = Vb + (size_t)srow * SEQ + c0 * 8;
  const unsigned short* vp1 = Vb + (size_t)(32 + srow) * SEQ + c0 * 8;
  unsigned short* ldK0 = &Ks[0][srow][sslot * 8];
  unsigned short* ldK1 = &Ks[0][32 + srow][sslot * 8];
  unsigned short* ldV0 = &Vs[0][srow][sslot * 8];
  unsigned short* ldV1 = &Vs[0][32 + srow][sslot * 8];
  int sbuf = 0;  // next staging buffer (STAGE called once per tile, in order)

#define STAGE() do {                                                        \
    load_lds16(kp0, (char*)ldK0 + sbuf * 8192);                             \
    load_lds16(kp1, (char*)ldK1 + sbuf * 8192);                             \
    load_lds16(vp0, (char*)ldV0 + sbuf * 8192);                             \
    load_lds16(vp1, (char*)ldV1 + sbuf * 8192);                             \
    kp0 += 64 * HD; kp1 += 64 * HD; vp0 += 64; vp1 += 64;                   \
    sbuf = (sbuf + 1) & 3;                                                  \
  } while (0)

// one K-tile: QK^T -> in-place softmax (exp2) -> pack -> PV (+row-sum MFMA)
#define TILE(buf, kb_t) do {                                                \
    f32x16 s0 = zv16, s1 = zv16;                                            \
    __builtin_amdgcn_s_setprio(1);                                          \
    _Pragma("unroll")                                                       \
    for (int dd = 0; dd < 4; ++dd) {                                        \
      bf16x8 kf0 = *(const bf16x8*)(kB + ((buf) * 8192) + offs[dd]);        \
      bf16x8 kf1 = *(const bf16x8*)(kB + ((buf) * 8192 + 4096) + offs[dd]); \
      s0 = __builtin_amdgcn_mfma_f32_32x32x16_bf16(kf0, qfr[dd], s0, 0, 0, 0);\
      s1 = __builtin_amdgcn_mfma_f32_32x32x16_bf16(kf1, qfr[dd], s1, 0, 0, 0);\
    }                                                                       \
    __builtin_amdgcn_s_setprio(0);                                          \
    if ((mapmask >> ((kb_t) >> 6)) & 1) {                                   \
      _Pragma("unroll")                                                     \
      for (int rg = 0; rg < 16; ++rg) {                                     \
        int kl = (rg & 3) + 8 * (rg >> 2) + 4 * hi;                         \
        if (maskrow[(kb_t) + kl] == 0)      s0[rg] = -__builtin_inff();     \
        if (maskrow[(kb_t) + 32 + kl] == 0) s1[rg] = -__builtin_inff();     \
      }                                                                     \
    }                                                                       \
    float t16[16];                                                          \
    _Pragma("unroll")                                                       \
    for (int j = 0; j < 16; ++j) t16[j] = fmaxf(s0[j], s1[j]);              \
    float t4[4];                                                            \
    _Pragma("unroll")                                                       \
    for (int j = 0; j < 4; ++j)                                             \
      t4[j] = fmaxf(fmaxf(t16[j], t16[j + 4]), fmaxf(t16[j + 8], t16[j + 12]));\
    float pmax = fmaxf(fmaxf(t4[0], t4[1]), fmaxf(t4[2], t4[3]));           \
    {                                                                       \
      u32x2 pm2 = __builtin_amdgcn_permlane32_swap(                         \
          __float_as_uint(pmax), __float_as_uint(pmax), false, false);      \
      pmax = fmaxf(__uint_as_float(pm2[0]), __uint_as_float(pm2[1]));       \
    }                                                                       \
    if (!__all(pmax <= mrun + 11.5f)) {                                     \
      float mnew = fmaxf(mrun, pmax);                                       \
      float corr = fexp2(mrun - mnew);                                      \
      mrun = mnew;                                                          \
      lrun *= corr;                                                         \
      _Pragma("unroll")                                                     \
      for (int dh = 0; dh < 2; ++dh)                                        \
        _Pragma("unroll")                                                   \
        for (int rg = 0; rg < 16; ++rg) oacc[dh][rg] *= corr;               \
    }                                                                       \
    _Pragma("unroll")                                                       \
    for (int rg = 0; rg < 16; ++rg) {                                       \
      s0[rg] = fexp2(s0[rg] - mrun);                                        \
      s1[rg] = fexp2(s1[rg] - mrun);                                        \
    }                                                                       \
    bf16x8 pfrag[4];                                                        \
    _Pragma("unroll")                                                       \
    for (int f = 0; f < 4; ++f) {  /* f = ks*2 + half */                    \
      const f32x16& sk = (f >> 1) ? s1 : s0;                                \
      int b0 = (f & 1) * 8;                                                 \
      unsigned w0 = cvtpk(sk[b0 + 0], sk[b0 + 1]);                          \
      unsigned w1 = cvtpk(sk[b0 + 2], sk[b0 + 3]);                          \
      unsigned w2 = cvtpk(sk[b0 + 4], sk[b0 + 5]);                          \
      unsigned w3 = cvtpk(sk[b0 + 6], sk[b0 + 7]);                          \
      u32x2 s02 = __builtin_amdgcn_permlane32_swap(w0, w2, false, false);   \
      u32x2 s13 = __builtin_amdgcn_permlane32_swap(w1, w3, false, false);   \
      union { unsigned u[4]; bf16x8 v; } fr;                                \
      fr.u[0] = s02[0]; fr.u[1] = s13[0]; fr.u[2] = s02[1]; fr.u[3] = s13[1];\
      pfrag[f] = fr.v;                                                      \
    }                                                                       \
    f32x16 lacc = zv16;                                                     \
    __builtin_amdgcn_s_setprio(1);                                          \
    _Pragma("unroll")                                                       \
    for (int f = 0; f < 4; ++f)                                             \
      lacc = __builtin_amdgcn_mfma_f32_32x32x16_bf16(onesf, pfrag[f], lacc, \
                                                     0, 0, 0);              \
    _Pragma("unroll")                                                       \
    for (int f = 0; f < 4; ++f) {                                           \
      bf16x8 vf0 = *(const bf16x8*)(vB + ((buf) * 8192) + offs[f]);         \
      bf16x8 vf1 = *(const bf16x8*)(vB + ((buf) * 8192 + 4096) + offs[f]);  \
      oacc[0] = __builtin_amdgcn_mfma_f32_32x32x16_bf16(vf0, pfrag[f],      \
                                                        oacc[0], 0, 0, 0);  \
      oacc[1] = __builtin_amdgcn_mfma_f32_32x32x16_bf16(vf1, pfrag[f],      \
                                                        oacc[1], 0, 0, 0);  \
    }                                                                       \
    __builtin_amdgcn_s_setprio(0);                                          \
    lrun += lacc[0];                                                        \
  } while (0)

// counted-vmcnt iteration: stage tile t+2, wait tile t done (leave 8 loads
// in flight), rendezvous, compute tile t.  VM must be a literal.
#define ITER(bufc, tv, DO_STAGE, VM) do {                                   \
    if (DO_STAGE) STAGE();                                                  \
    asm volatile("s_waitcnt vmcnt(" #VM ")" ::: "memory");                  \
    __builtin_amdgcn_s_barrier();                                           \
    TILE(bufc, (tv) * 64);                                                  \
  } while (0)

  STAGE();  // tile 0
  STAGE();  // tile 1

  for (int tt = 0; tt < 28; tt += 4) {
    ITER(0, tt + 0, 1, 8);
    ITER(1, tt + 1, 1, 8);
    ITER(2, tt + 2, 1, 8);
    ITER(3, tt + 3, 1, 8);
  }
  ITER(0, 28, 1, 8);   // stages tile 30
  ITER(1, 29, 1, 8);   // stages tile 31
  ITER(2, 30, 0, 4);
  ITER(3, 31, 0, 0);

  const float rl = 1.0f / lrun;
  const int b = bh >> 4, h = bh & 15;
  unsigned short* orow = O + (size_t)(b * SEQ + q0w + q) * HID + h * HD;
#pragma unroll
  for (int dh = 0; dh < 2; ++dh)
#pragma unroll
    for (int r2 = 0; r2 < 4; ++r2) {
      float v0 = oacc[dh][r2 * 4 + 0] * rl;
      float v1 = oacc[dh][r2 * 4 + 1] * rl;
      float v2 = oacc[dh][r2 * 4 + 2] * rl;
      float v3 = oacc[dh][r2 * 4 + 3] * rl;
      u32x2 pk;
      pk[0] = (unsigned)f2bf(v0) | ((unsigned)f2bf(v1) << 16);
      pk[1] = (unsigned)f2bf(v2) | ((unsigned)f2bf(v3) << 16);
      *reinterpret_cast<u32x2*>(orow + dh * 32 + r2 * 8 + hi * 4) = pk;
    }
#undef STAGE
#undef TILE
#undef ITER
}

// ---------------- launch -----------------------------------------------------
extern "C" void kernel_launch(void* const* d_in, const int* in_sizes, int n_in,
                              void* d_out, int out_size, void* d_ws, size_t ws_size,
                              hipStream_t stream) {
  const float* x    = (const float*)d_in[0];
  const int*   mask = (const int*)d_in[1];
  const float* Wq   = (const float*)d_in[2];
  const float* bq   = (const float*)d_in[3];
  const float* Wk   = (const float*)d_in[4];
  const float* bk   = (const float*)d_in[5];
  const float* Wv   = (const float*)d_in[6];
  const float* bv   = (const float*)d_in[7];
  const float* Wo   = (const float*)d_in[8];
  const float* bo   = (const float*)d_in[9];
  float* out = (float*)d_out;

  unsigned short* ws = (unsigned short*)d_ws;
  unsigned short* xb = ws;                      // 4194304 bf16
  unsigned short* wb = ws + 4194304;            // 4 x 1048576 (Wq,Wk,Wv,Wo)
  unsigned short* Qd = ws + 8388608;            // [32][2048][64] (pre-scaled)
  unsigned short* Kd = ws + 12582912;           // [32][2048][64]
  unsigned short* Vt = ws + 16777216;           // [32][64][2048]
  unsigned short* Ob = ws + 20971520;           // [4096][1024]
  int* map = (int*)(ws + 25165824);             // [32][32]

  convert_and_mask<<<5120, 256, 0, stream>>>(x, Wq, Wk, Wv, Wo, mask, ws, map);
  gemm_qkv<<<dim3(24, 32), 256, 0, stream>>>(xb, wb, bq, bk, bv, Qd, Kd, Vt);
  flash_attn<<<512, 256, 0, stream>>>(Qd, Kd, Vt, map, mask, Ob);
  gemm_out<<<dim3(16, 32), 256, 0, stream>>>(Ob, wb + 3 * 1048576, bo, out);
}